// Round 17
// baseline (2434.728 us; speedup 1.0000x reference)
//
#include <hip/hip_runtime.h>

// Sizes (fixed): V=512, F_IN=8, H=64, DH=4, T=3, E=8192, P=64, L=8, D=68

typedef __attribute__((ext_vector_type(8))) short bf16x8;
typedef __attribute__((ext_vector_type(4))) float f32x4;

__device__ __forceinline__ float fsig_(float x) { return 1.f / (1.f + __expf(-x)); }
__device__ __forceinline__ float ftanh_(float x) {
  float e = __expf(2.f * x);
  return 1.f - 2.f / (e + 1.f);
}
__device__ __forceinline__ float sig_(float x) { return 1.f / (1.f + expf(-x)); }

// f32 -> bf16 with round-to-nearest-even.
__device__ __forceinline__ unsigned short f2bf(float f) {
  union { float f; unsigned u; } a; a.f = f;
  unsigned r = a.u + 0x7FFFu + ((a.u >> 16) & 1u);
  return (unsigned short)(r >> 16);
}

// Barrier WITHOUT vmcnt drain: LDS ordering only.
__device__ __forceinline__ void barrier_lgkm() {
  asm volatile("s_waitcnt lgkmcnt(0)\n\ts_barrier" ::: "memory");
}

#define MFMA16(a, b, c) __builtin_amdgcn_mfma_f32_16x16x32_bf16((a), (b), (c), 0, 0, 0)

// NOTE: macro params must NOT collide with float4 member names (x/y/z/w).
#define LD4(p) (*(const float4*)(p))

// x[i,j,h] = sum_f adj[i,j,f] * emb[h,f]
__global__ __launch_bounds__(256) void embed_kernel(
    const float* __restrict__ adj, const float* __restrict__ emb,
    float* __restrict__ x)
{
  const int64_t row = (int64_t)blockIdx.x * 4 + (threadIdx.x >> 6);
  const int h = threadIdx.x & 63;
  const float* a = adj + row * 8;
  float acc = 0.f;
#pragma unroll
  for (int f = 0; f < 8; ++f) acc += a[f] * emb[h * 8 + f];
  x[row * 64 + h] = acc;
}

// col_sum[j,h] = sum_i x[i,j,h];  col_nz[j] = sum_i sum_h (x[i,j,h]!=0)
__global__ __launch_bounds__(256) void colsum_kernel(
    const float* __restrict__ x, float* __restrict__ col_sum,
    int* __restrict__ col_nz)
{
  const int j = blockIdx.x;
  const int h = threadIdx.x & 63;
  const int w = threadIdx.x >> 6;
  float acc = 0.f;
  int nz = 0;
  for (int i = w; i < 512; i += 4) {
    float v = x[((int64_t)i * 512 + j) * 64 + h];
    acc += v;
    nz += (v != 0.f) ? 1 : 0;
  }
  __shared__ float pacc[4][64];
  __shared__ int pnz[4];
#pragma unroll
  for (int off = 32; off > 0; off >>= 1) nz += __shfl_down(nz, off, 64);
  if (h == 0) pnz[w] = nz;
  pacc[w][h] = acc;
  __syncthreads();
  if (w == 0) {
    col_sum[j * 64 + h] = pacc[0][h] + pacc[1][h] + pacc[2][h] + pacc[3][h];
    if (h == 0) col_nz[j] = pnz[0] + pnz[1] + pnz[2] + pnz[3];
  }
}

__global__ void scatter_idx_kernel(const int* __restrict__ edges,
                                   int* __restrict__ idxmap)
{
  const int e = blockIdx.x * 256 + threadIdx.x;
  if (e < 8192) idxmap[edges[e * 2] * 512 + edges[e * 2 + 1]] = e;
}

// Per-edge message m_e, then delta_gi[e,g] = sum_h (m_e[h]-x_uv[h]) * w_ih[g,h]
// 4 edges per block, one 64-lane wave each (ballot/popc are per-wave).
__global__ __launch_bounds__(256) void edge_kernel(
    const float* __restrict__ x, const int* __restrict__ edges,
    const float* __restrict__ col_sum, const int* __restrict__ col_nz,
    const float* __restrict__ w1, const float* __restrict__ w2,
    const float* __restrict__ w3, const float* __restrict__ w_ih,
    float* __restrict__ delta_gi)
{
  const int wv = threadIdx.x >> 6;
  const int e = blockIdx.x * 4 + wv;
  const int h = threadIdx.x & 63;
  const int u = edges[e * 2 + 0];
  const int v = edges[e * 2 + 1];
  __shared__ __align__(16) float xuv[4][64], ein[4][64], eout[4][64], dm[4][64];
  const float xuvh = x[((int64_t)u * 512 + v) * 64 + h];
  const float xvuh = x[((int64_t)v * 512 + u) * 64 + h];
  xuv[wv][h] = xuvh;
  const int nz_vu = __popcll(__ballot(xvuh != 0.f));
  const int nz_uv = __popcll(__ballot(xuvh != 0.f));
  float n_in = (float)(col_nz[u] - nz_vu) / 64.f;
  if (n_in == 0.f) n_in = 1.f;
  float n_out = (float)(col_nz[v] - nz_uv) / 64.f;
  if (n_out == 0.f) n_out = 1.f;
  ein[wv][h] = (col_sum[u * 64 + h] - xvuh) / n_in;
  eout[wv][h] = (col_sum[v * 64 + h] - xuvh) / n_out;
  __syncthreads();
  const float4* w1r = (const float4*)(w1 + h * 64);
  const float4* w2r = (const float4*)(w2 + h * 64);
  const float4* w3r = (const float4*)(w3 + h * 64);
  const float4* xuv4 = (const float4*)&xuv[wv][0];
  const float4* ein4 = (const float4*)&ein[wv][0];
  const float4* eout4 = (const float4*)&eout[wv][0];
  float acc = 0.f;
#pragma unroll
  for (int kk = 0; kk < 16; ++kk) {
    float4 a = xuv4[kk], b = w1r[kk];
    acc += a.x * b.x + a.y * b.y + a.z * b.z + a.w * b.w;
    a = ein4[kk]; b = w2r[kk];
    acc += a.x * b.x + a.y * b.y + a.z * b.z + a.w * b.w;
    a = eout4[kk]; b = w3r[kk];
    acc += a.x * b.x + a.y * b.y + a.z * b.z + a.w * b.w;
  }
  const float m = fmaxf(acc, 0.f);
  dm[wv][h] = m - xuvh;
  __syncthreads();
  const float4* dm4 = (const float4*)&dm[wv][0];
#pragma unroll
  for (int r = 0; r < 3; ++r) {
    const int gg = h + r * 64;
    const float4* wr = (const float4*)(w_ih + gg * 128);
    float d = 0.f;
#pragma unroll
    for (int kk = 0; kk < 16; ++kk) {
      float4 a = dm4[kk], b = wr[kk];
      d += a.x * b.x + a.y * b.y + a.z * b.z + a.w * b.w;
    }
    delta_gi[e * 192 + gg] = d;
  }
}

// ---- GRU scan v12: MFMA batch-row scan. ----
// 16 rows per block, grid 32, 256 thr = 4 waves. Per step: 16x192 gate
// pre-activations via 12 mfma_f32_16x16x32_bf16 (wave w owns gate-units
// u = 16w..16w+15; r/z accumulate x-side+h-side; n keeps them separate).
// Fragment layouts (gfx950, 16x16x32 bf16):
//   A: row = lane&15, k = (lane>>4)*8 + j   (8 contiguous k per lane)
//   B: col = lane&15, k = (lane>>4)*8 + j
//   C: col = lane&15, row = 4*(lane>>4) + reg   [HW-verified, m89/m91]
// Each lane owns the SAME 4 (row,unit) cells every step -> h_old in regs.
// h redistributed to A-layout via a 2KB swizzled LDS buffer; x(t) read
// fp32 (prefetched 1 step ahead) and converted to bf16 in-register.
__global__ __launch_bounds__(256) void scan_mfma_kernel(
    float* __restrict__ x, const float* __restrict__ delta_gi,
    const int* __restrict__ idxmap,
    const float* __restrict__ w_ih, const float* __restrict__ w_hh,
    const float* __restrict__ b_ih, const float* __restrict__ b_hh)
{
  const int tid = threadIdx.x;
  const int wv = tid >> 6;
  const int l = tid & 63;
  const int cl = l & 15;
  const int kg = l >> 4;
  const int b0 = blockIdx.x * 16;
  const int u = wv * 16 + cl;  // gate-unit owned by this lane

  __shared__ unsigned short h_lds[16 * 64];  // A-layout, swizzled, 2KB
  __shared__ int idxl[16][512];              // 32KB

  for (int i = tid; i < 8192; i += 256)
    idxl[i >> 9][i & 511] = idxmap[(int64_t)(b0 + (i >> 9)) * 512 + (i & 511)];
  for (int i = tid; i < 512; i += 256) ((unsigned*)h_lds)[i] = 0;

  // 12 B-fragments: B[k][c] = W[c][k]; this lane: c=u (+0/64/128 gate class),
  // k = kst*32 + kg*8 + j.
  bf16x8 BXr0, BXr1, BXz0, BXz1, BXn0, BXn1;
  bf16x8 BHr0, BHr1, BHz0, BHz1, BHn0, BHn1;
  {
    union { bf16x8 v; unsigned short s[8]; } t0, t1, t2, t3, t4, t5;
#define FILLB(kst)                                                             \
    _Pragma("unroll")                                                          \
    for (int j = 0; j < 8; ++j) {                                              \
      const int k = (kst) * 32 + kg * 8 + j;                                   \
      t0.s[j] = f2bf(w_ih[u * 128 + k] + w_ih[u * 128 + 64 + k]);              \
      t1.s[j] = f2bf(w_ih[(64 + u) * 128 + k] + w_ih[(64 + u) * 128 + 64 + k]);\
      t2.s[j] = f2bf(w_ih[(128 + u) * 128 + k] +                               \
                     w_ih[(128 + u) * 128 + 64 + k]);                          \
      t3.s[j] = f2bf(w_hh[u * 64 + k]);                                        \
      t4.s[j] = f2bf(w_hh[(64 + u) * 64 + k]);                                 \
      t5.s[j] = f2bf(w_hh[(128 + u) * 64 + k]);                                \
    }
    FILLB(0)
    BXr0 = t0.v; BXz0 = t1.v; BXn0 = t2.v;
    BHr0 = t3.v; BHz0 = t4.v; BHn0 = t5.v;
    FILLB(1)
    BXr1 = t0.v; BXz1 = t1.v; BXn1 = t2.v;
    BHr1 = t3.v; BHz1 = t4.v; BHn1 = t5.v;
#undef FILLB
  }
  const float brz_r = b_ih[u] + b_hh[u];
  const float brz_z = b_ih[64 + u] + b_hh[64 + u];
  const float bin = b_ih[128 + u];
  const float bhn = b_hh[128 + u];

  const float* xarow = x + (int64_t)(b0 + cl) * 32768;  // A row = cl
  float4 XF0a = LD4(xarow + kg * 8);
  float4 XF0b = LD4(xarow + kg * 8 + 4);
  float4 XF1a = LD4(xarow + 32 + kg * 8);
  float4 XF1b = LD4(xarow + 32 + kg * 8 + 4);
  float ho[4] = {0.f, 0.f, 0.f, 0.f};
  const int swz = (cl & 7) << 4;  // A-read swizzle (row = cl)
  __syncthreads();

  for (int t = 0; t < 512; ++t) {
    // H(t-1) A-frags from swizzled LDS
    bf16x8 HA0 = *(const bf16x8*)((const char*)h_lds + cl * 128 +
                                  ((kg * 16) ^ swz));
    bf16x8 HA1 = *(const bf16x8*)((const char*)h_lds + cl * 128 +
                                  ((64 + kg * 16) ^ swz));
    // delta prefetch (L2; overlapped with MFMA)
    float dR[4], dZ[4], dN[4];
#pragma unroll
    for (int i = 0; i < 4; ++i) {
      const int idx = idxl[4 * kg + i][t];
      if (idx >= 0) {
        const float* dp = delta_gi + (int64_t)idx * 192;
        dR[i] = dp[u]; dZ[i] = dp[64 + u]; dN[i] = dp[128 + u];
      } else { dR[i] = 0.f; dZ[i] = 0.f; dN[i] = 0.f; }
    }
    // cvt prefetched X(t) to bf16 A-frags
    union { bf16x8 v; unsigned short s[8]; } xa0, xa1;
    xa0.s[0] = f2bf(XF0a.x); xa0.s[1] = f2bf(XF0a.y);
    xa0.s[2] = f2bf(XF0a.z); xa0.s[3] = f2bf(XF0a.w);
    xa0.s[4] = f2bf(XF0b.x); xa0.s[5] = f2bf(XF0b.y);
    xa0.s[6] = f2bf(XF0b.z); xa0.s[7] = f2bf(XF0b.w);
    xa1.s[0] = f2bf(XF1a.x); xa1.s[1] = f2bf(XF1a.y);
    xa1.s[2] = f2bf(XF1a.z); xa1.s[3] = f2bf(XF1a.w);
    xa1.s[4] = f2bf(XF1b.x); xa1.s[5] = f2bf(XF1b.y);
    xa1.s[6] = f2bf(XF1b.z); xa1.s[7] = f2bf(XF1b.w);
    // 12 MFMA
    f32x4 zz = {0.f, 0.f, 0.f, 0.f};
    f32x4 aR = MFMA16(xa0.v, BXr0, zz); aR = MFMA16(xa1.v, BXr1, aR);
    aR = MFMA16(HA0, BHr0, aR);         aR = MFMA16(HA1, BHr1, aR);
    f32x4 aZ = MFMA16(xa0.v, BXz0, zz); aZ = MFMA16(xa1.v, BXz1, aZ);
    aZ = MFMA16(HA0, BHz0, aZ);         aZ = MFMA16(HA1, BHz1, aZ);
    f32x4 aNX = MFMA16(xa0.v, BXn0, zz); aNX = MFMA16(xa1.v, BXn1, aNX);
    f32x4 aNH = MFMA16(HA0, BHn0, zz);   aNH = MFMA16(HA1, BHn1, aNH);
    // prefetch X(t+1) fp32
    const int tn = (t + 1 < 512) ? t + 1 : 511;
    XF0a = LD4(xarow + tn * 64 + kg * 8);
    XF0b = LD4(xarow + tn * 64 + kg * 8 + 4);
    XF1a = LD4(xarow + tn * 64 + 32 + kg * 8);
    XF1b = LD4(xarow + tn * 64 + 32 + kg * 8 + 4);
    barrier_lgkm();  // all waves' h_lds reads complete
    // activations + h update + writes
#pragma unroll
    for (int i = 0; i < 4; ++i) {
      const float r = fsig_(aR[i] + brz_r + dR[i]);
      const float zg = fsig_(aZ[i] + brz_z + dZ[i]);
      const float nn = ftanh_(aNX[i] + bin + dN[i] + r * (aNH[i] + bhn));
      const float hn = (1.f - zg) * nn + zg * ho[i];
      ho[i] = hn;
      const int row = 4 * kg + i;
      *(unsigned short*)((char*)h_lds + row * 128 +
                         ((u * 2) ^ ((row & 7) << 4))) = f2bf(hn);
      x[(int64_t)(b0 + row) * 32768 + t * 64 + u] = hn;
    }
    // Ensure our X(t+1) prefetch loads completed before any wave can write
    // slot t+1 next step (4 newest outstanding = the 4 stores above).
    asm volatile("s_waitcnt vmcnt(4)" ::: "memory");
    barrier_lgkm();  // h(t) published
  }
}

// One block per (path, direction). 7-step GRU, D=68, gates 204.
// graph_emb computed inline from col_sum.
__global__ __launch_bounds__(256) void path_kernel(
    const float* __restrict__ x, const int* __restrict__ paths,
    const float* __restrict__ demands, const float* __restrict__ wd,
    const float* __restrict__ col_sum,
    const float* __restrict__ wih_f, const float* __restrict__ whh_f,
    const float* __restrict__ bih_f, const float* __restrict__ bhh_f,
    const float* __restrict__ wih_b, const float* __restrict__ whh_b,
    const float* __restrict__ bih_b, const float* __restrict__ bhh_b,
    float* __restrict__ h_out)
{
  const int p = blockIdx.x & 63;
  const int dir = blockIdx.x >> 6;
  const int g = threadIdx.x;
  const float* w_ih = dir ? wih_b : wih_f;
  const float* w_hh = dir ? whh_b : whh_f;
  const float* bih = dir ? bih_b : bih_f;
  const float* bhh = dir ? bhh_b : bhh_f;
  __shared__ float feat[7][68], hs[68], rbuf[68], zbuf[68];
  if (g < 64) {
    float s = 0.f;
#pragma unroll 8
    for (int jj = 0; jj < 512; ++jj) s += col_sum[jj * 64 + g];
    hs[g] = s * (1.f / 262144.f);
  } else if (g < 68) {
    hs[g] = 0.f;
  }
  if (g < 68) {
#pragma unroll
    for (int t = 0; t < 7; ++t) {
      const int src = paths[p * 8 + t];
      const int dst = paths[p * 8 + t + 1];
      feat[t][g] = (g < 64) ? x[((int64_t)src * 512 + dst) * 64 + g]
                            : fmaxf(demands[p] * wd[g - 64], 0.f);
    }
  }
  __syncthreads();
  for (int s = 0; s < 7; ++s) {
    const int t = dir ? (6 - s) : s;
    float acc = 0.f, hacc = 0.f;
    if (g < 204) {
      acc = bih[g];
      hacc = bhh[g];
      for (int k = 0; k < 68; ++k) {
        acc += feat[t][k] * w_ih[g * 68 + k];
        hacc += hs[k] * w_hh[g * 68 + k];
      }
    }
    if (g < 68) rbuf[g] = sig_(acc + hacc);
    else if (g < 136) zbuf[g - 68] = sig_(acc + hacc);
    __syncthreads();
    if (g >= 136 && g < 204) {
      const int j = g - 136;
      const float n = tanhf(acc + rbuf[j] * hacc);
      const float z = zbuf[j];
      const float hn = (1.f - z) * n + z * hs[j];
      hs[j] = hn;
    }
    __syncthreads();
  }
  if (g < 68) h_out[(dir * 64 + p) * 68 + g] = hs[g];
}

__global__ __launch_bounds__(64) void combine_kernel(
    const float* __restrict__ h_out, const float* __restrict__ wq,
    const float* __restrict__ bq, float* __restrict__ out)
{
  const int p = threadIdx.x;
  float l = bq[0];
#pragma unroll
  for (int d = 0; d < 68; ++d)
    l += 0.5f * (h_out[p * 68 + d] + h_out[(64 + p) * 68 + d]) * wq[d];
  float mx = l;
#pragma unroll
  for (int off = 32; off > 0; off >>= 1) mx = fmaxf(mx, __shfl_xor(mx, off, 64));
  const float e = expf(l - mx);
  float s = e;
#pragma unroll
  for (int off = 32; off > 0; off >>= 1) s += __shfl_xor(s, off, 64);
  out[p] = e / s;
}

extern "C" void kernel_launch(void* const* d_in, const int* in_sizes, int n_in,
                              void* d_out, int out_size, void* d_ws, size_t ws_size,
                              hipStream_t stream)
{
  const float* adj = (const float*)d_in[0];
  const int* edges = (const int*)d_in[1];
  const int* paths = (const int*)d_in[2];
  const float* demands = (const float*)d_in[3];
  const float* emb_w = (const float*)d_in[4];
  const float* w1s = (const float*)d_in[5];
  const float* w2s = (const float*)d_in[6];
  const float* w3s = (const float*)d_in[7];
  const float* gru_w_ih = (const float*)d_in[8];
  const float* gru_w_hh = (const float*)d_in[9];
  const float* gru_b_ih = (const float*)d_in[10];
  const float* gru_b_hh = (const float*)d_in[11];
  const float* pf_w_ih = (const float*)d_in[12];
  const float* pf_w_hh = (const float*)d_in[13];
  const float* pf_b_ih = (const float*)d_in[14];
  const float* pf_b_hh = (const float*)d_in[15];
  const float* pb_w_ih = (const float*)d_in[16];
  const float* pb_w_hh = (const float*)d_in[17];
  const float* pb_b_ih = (const float*)d_in[18];
  const float* pb_b_hh = (const float*)d_in[19];
  const float* wq = (const float*)d_in[20];
  const float* bq = (const float*)d_in[21];
  const float* wd = (const float*)d_in[22];
  float* out = (float*)d_out;

  // Workspace layout (floats): ~74.6 MB total (known-safe size)
  float* xA = (float*)d_ws;                    // 512*512*64 = 16777216
  float* col_sum = xA + 16777216;              // 32768
  int* col_nz = (int*)(col_sum + 32768);       // 512
  int* idxmap = col_nz + 512;                  // 262144
  float* delta_gi = (float*)(idxmap + 262144); // 8192*192 = 1572864
  float* h_out = delta_gi + 1572864;           // 2*64*68 = 8704

  hipMemsetAsync(idxmap, 0xFF, 262144 * sizeof(int), stream);
  scatter_idx_kernel<<<32, 256, 0, stream>>>(edges, idxmap);
  embed_kernel<<<65536, 256, 0, stream>>>(adj, emb_w, xA);

  for (int t = 0; t < 3; ++t) {
    colsum_kernel<<<512, 256, 0, stream>>>(xA, col_sum, col_nz);
    edge_kernel<<<2048, 256, 0, stream>>>(xA, edges, col_sum, col_nz,
        w1s + t * 4096, w2s + t * 4096, w3s + t * 4096, gru_w_ih, delta_gi);
    scan_mfma_kernel<<<32, 256, 0, stream>>>(xA, delta_gi, idxmap,
        gru_w_ih, gru_w_hh, gru_b_ih, gru_b_hh);
  }

  colsum_kernel<<<512, 256, 0, stream>>>(xA, col_sum, col_nz);
  path_kernel<<<128, 256, 0, stream>>>(xA, paths, demands, wd, col_sum,
      pf_w_ih, pf_w_hh, pf_b_ih, pf_b_hh,
      pb_w_ih, pb_w_hh, pb_b_ih, pb_b_hh, h_out);
  combine_kernel<<<1, 64, 0, stream>>>(h_out, wq, bq, out);
}

// Round 18
// 2327.366 us; speedup vs baseline: 1.0461x; 1.0461x over previous
//
#include <hip/hip_runtime.h>

// Sizes (fixed): V=512, F_IN=8, H=64, DH=4, T=3, E=8192, P=64, L=8, D=68

typedef __attribute__((ext_vector_type(8))) short bf16x8;
typedef __attribute__((ext_vector_type(4))) float f32x4;

__device__ __forceinline__ float fsig_(float x) { return 1.f / (1.f + __expf(-x)); }
__device__ __forceinline__ float ftanh_(float x) {
  float e = __expf(2.f * x);
  return 1.f - 2.f / (e + 1.f);
}
__device__ __forceinline__ float sig_(float x) { return 1.f / (1.f + expf(-x)); }

// f32 -> bf16 with round-to-nearest-even.
__device__ __forceinline__ unsigned short f2bf(float f) {
  union { float f; unsigned u; } a; a.f = f;
  unsigned r = a.u + 0x7FFFu + ((a.u >> 16) & 1u);
  return (unsigned short)(r >> 16);
}

// Barrier WITHOUT vmcnt drain: LDS ordering only.
__device__ __forceinline__ void barrier_lgkm() {
  asm volatile("s_waitcnt lgkmcnt(0)\n\ts_barrier" ::: "memory");
}

#define MFMA16(a, b, c) __builtin_amdgcn_mfma_f32_16x16x32_bf16((a), (b), (c), 0, 0, 0)

// NOTE: macro params must NOT collide with float4 member names (x/y/z/w).
#define LD4(p) (*(const float4*)(p))

// x[i,j,h] = sum_f adj[i,j,f] * emb[h,f]
__global__ __launch_bounds__(256) void embed_kernel(
    const float* __restrict__ adj, const float* __restrict__ emb,
    float* __restrict__ x)
{
  const int64_t row = (int64_t)blockIdx.x * 4 + (threadIdx.x >> 6);
  const int h = threadIdx.x & 63;
  const float* a = adj + row * 8;
  float acc = 0.f;
#pragma unroll
  for (int f = 0; f < 8; ++f) acc += a[f] * emb[h * 8 + f];
  x[row * 64 + h] = acc;
}

// col_sum[j,h] = sum_i x[i,j,h];  col_nz[j] = sum_i sum_h (x[i,j,h]!=0)
__global__ __launch_bounds__(256) void colsum_kernel(
    const float* __restrict__ x, float* __restrict__ col_sum,
    int* __restrict__ col_nz)
{
  const int j = blockIdx.x;
  const int h = threadIdx.x & 63;
  const int w = threadIdx.x >> 6;
  float acc = 0.f;
  int nz = 0;
  for (int i = w; i < 512; i += 4) {
    float v = x[((int64_t)i * 512 + j) * 64 + h];
    acc += v;
    nz += (v != 0.f) ? 1 : 0;
  }
  __shared__ float pacc[4][64];
  __shared__ int pnz[4];
#pragma unroll
  for (int off = 32; off > 0; off >>= 1) nz += __shfl_down(nz, off, 64);
  if (h == 0) pnz[w] = nz;
  pacc[w][h] = acc;
  __syncthreads();
  if (w == 0) {
    col_sum[j * 64 + h] = pacc[0][h] + pacc[1][h] + pacc[2][h] + pacc[3][h];
    if (h == 0) col_nz[j] = pnz[0] + pnz[1] + pnz[2] + pnz[3];
  }
}

__global__ void scatter_idx_kernel(const int* __restrict__ edges,
                                   int* __restrict__ idxmap)
{
  const int e = blockIdx.x * 256 + threadIdx.x;
  if (e < 8192) idxmap[edges[e * 2] * 512 + edges[e * 2 + 1]] = e;
}

// Per-edge message m_e, then delta_gi[e,g] = sum_h (m_e[h]-x_uv[h]) * w_ih[g,h]
// 4 edges per block, one 64-lane wave each (ballot/popc are per-wave).
__global__ __launch_bounds__(256) void edge_kernel(
    const float* __restrict__ x, const int* __restrict__ edges,
    const float* __restrict__ col_sum, const int* __restrict__ col_nz,
    const float* __restrict__ w1, const float* __restrict__ w2,
    const float* __restrict__ w3, const float* __restrict__ w_ih,
    float* __restrict__ delta_gi)
{
  const int wv = threadIdx.x >> 6;
  const int e = blockIdx.x * 4 + wv;
  const int h = threadIdx.x & 63;
  const int u = edges[e * 2 + 0];
  const int v = edges[e * 2 + 1];
  __shared__ __align__(16) float xuv[4][64], ein[4][64], eout[4][64], dm[4][64];
  const float xuvh = x[((int64_t)u * 512 + v) * 64 + h];
  const float xvuh = x[((int64_t)v * 512 + u) * 64 + h];
  xuv[wv][h] = xuvh;
  const int nz_vu = __popcll(__ballot(xvuh != 0.f));
  const int nz_uv = __popcll(__ballot(xuvh != 0.f));
  float n_in = (float)(col_nz[u] - nz_vu) / 64.f;
  if (n_in == 0.f) n_in = 1.f;
  float n_out = (float)(col_nz[v] - nz_uv) / 64.f;
  if (n_out == 0.f) n_out = 1.f;
  ein[wv][h] = (col_sum[u * 64 + h] - xvuh) / n_in;
  eout[wv][h] = (col_sum[v * 64 + h] - xuvh) / n_out;
  __syncthreads();
  const float4* w1r = (const float4*)(w1 + h * 64);
  const float4* w2r = (const float4*)(w2 + h * 64);
  const float4* w3r = (const float4*)(w3 + h * 64);
  const float4* xuv4 = (const float4*)&xuv[wv][0];
  const float4* ein4 = (const float4*)&ein[wv][0];
  const float4* eout4 = (const float4*)&eout[wv][0];
  float acc = 0.f;
#pragma unroll
  for (int kk = 0; kk < 16; ++kk) {
    float4 a = xuv4[kk], b = w1r[kk];
    acc += a.x * b.x + a.y * b.y + a.z * b.z + a.w * b.w;
    a = ein4[kk]; b = w2r[kk];
    acc += a.x * b.x + a.y * b.y + a.z * b.z + a.w * b.w;
    a = eout4[kk]; b = w3r[kk];
    acc += a.x * b.x + a.y * b.y + a.z * b.z + a.w * b.w;
  }
  const float m = fmaxf(acc, 0.f);
  dm[wv][h] = m - xuvh;
  __syncthreads();
  const float4* dm4 = (const float4*)&dm[wv][0];
#pragma unroll
  for (int r = 0; r < 3; ++r) {
    const int gg = h + r * 64;
    const float4* wr = (const float4*)(w_ih + gg * 128);
    float d = 0.f;
#pragma unroll
    for (int kk = 0; kk < 16; ++kk) {
      float4 a = dm4[kk], b = wr[kk];
      d += a.x * b.x + a.y * b.y + a.z * b.z + a.w * b.w;
    }
    delta_gi[e * 192 + gg] = d;
  }
}

// ---- GRU scan v13: MFMA batch-row scan, pipelined. ----
// Same verified math/layouts as v12 (r17: absmax 6.1e-5). Changes:
//  * delta prefetched ONE STEP AHEAD (clamped unconditional -> fixed vmcnt)
//  * h_lds double-buffered -> ONE barrier per step
//  * h_lds padded [16][72] shorts (16B-aligned b128 reads, no XOR swizzle)
//  * counted vmcnt(16): {12 delta(t+1) + 4 stores} stay in flight across the
//    barrier; x(t+1) retires before it (kills in-place RAW race cheaply)
__global__ __launch_bounds__(256) void scan_mfma_kernel(
    float* __restrict__ x, const float* __restrict__ delta_gi,
    const int* __restrict__ idxmap,
    const float* __restrict__ w_ih, const float* __restrict__ w_hh,
    const float* __restrict__ b_ih, const float* __restrict__ b_hh)
{
  const int tid = threadIdx.x;
  const int wv = tid >> 6;
  const int l = tid & 63;
  const int cl = l & 15;
  const int kg = l >> 4;
  const int b0 = blockIdx.x * 16;
  const int u = wv * 16 + cl;  // gate-unit owned by this lane

  __shared__ __align__(16) unsigned short h_lds[2][16 * 72];  // dbuf, padded
  __shared__ int idxl[16][512];                               // 32KB

  for (int i = tid; i < 8192; i += 256)
    idxl[i >> 9][i & 511] = idxmap[(int64_t)(b0 + (i >> 9)) * 512 + (i & 511)];
  for (int i = tid; i < 1152; i += 256) ((unsigned*)h_lds)[i] = 0;

  // 12 B-fragments (verified r17): B[k][c]=W[c][k]; lane: c=u, k=kst*32+kg*8+j
  bf16x8 BXr0, BXr1, BXz0, BXz1, BXn0, BXn1;
  bf16x8 BHr0, BHr1, BHz0, BHz1, BHn0, BHn1;
  {
    union { bf16x8 v; unsigned short s[8]; } t0, t1, t2, t3, t4, t5;
#define FILLB(kst)                                                             \
    _Pragma("unroll")                                                          \
    for (int j = 0; j < 8; ++j) {                                              \
      const int k = (kst) * 32 + kg * 8 + j;                                   \
      t0.s[j] = f2bf(w_ih[u * 128 + k] + w_ih[u * 128 + 64 + k]);              \
      t1.s[j] = f2bf(w_ih[(64 + u) * 128 + k] + w_ih[(64 + u) * 128 + 64 + k]);\
      t2.s[j] = f2bf(w_ih[(128 + u) * 128 + k] +                               \
                     w_ih[(128 + u) * 128 + 64 + k]);                          \
      t3.s[j] = f2bf(w_hh[u * 64 + k]);                                        \
      t4.s[j] = f2bf(w_hh[(64 + u) * 64 + k]);                                 \
      t5.s[j] = f2bf(w_hh[(128 + u) * 64 + k]);                                \
    }
    FILLB(0)
    BXr0 = t0.v; BXz0 = t1.v; BXn0 = t2.v;
    BHr0 = t3.v; BHz0 = t4.v; BHn0 = t5.v;
    FILLB(1)
    BXr1 = t0.v; BXz1 = t1.v; BXn1 = t2.v;
    BHr1 = t3.v; BHz1 = t4.v; BHn1 = t5.v;
#undef FILLB
  }
  const float brz_r = b_ih[u] + b_hh[u];
  const float brz_z = b_ih[64 + u] + b_hh[64 + u];
  const float bin = b_ih[128 + u];
  const float bhn = b_hh[128 + u];

  const float* xarow = x + (int64_t)(b0 + cl) * 32768;  // A row = cl
  float4 XF0a = LD4(xarow + kg * 8);
  float4 XF0b = LD4(xarow + kg * 8 + 4);
  float4 XF1a = LD4(xarow + 32 + kg * 8);
  float4 XF1b = LD4(xarow + 32 + kg * 8 + 4);
  float ho[4] = {0.f, 0.f, 0.f, 0.f};
  __syncthreads();  // idxl + h_lds zero sealed

  // delta(0) prefetch (clamped unconditional + sign mask)
  float dR[4], dZ[4], dN[4];
  int msk[4];
#pragma unroll
  for (int i = 0; i < 4; ++i) {
    const int idx = idxl[4 * kg + i][0];
    msk[i] = (idx >= 0);
    const float* dp = delta_gi + (int64_t)(idx < 0 ? 0 : idx) * 192;
    dR[i] = dp[u]; dZ[i] = dp[64 + u]; dN[i] = dp[128 + u];
  }

  for (int t = 0; t < 512; ++t) {
    // H(t-1) A-frags from double buffer (written at t-1 into buf[(t-1)&1])
    const char* hb = (const char*)h_lds[(t + 1) & 1];
    bf16x8 HA0 = *(const bf16x8*)(hb + cl * 144 + kg * 16);
    bf16x8 HA1 = *(const bf16x8*)(hb + cl * 144 + 64 + kg * 16);
    // cvt prefetched X(t) to bf16 A-frags
    union { bf16x8 v; unsigned short s[8]; } xa0, xa1;
    xa0.s[0] = f2bf(XF0a.x); xa0.s[1] = f2bf(XF0a.y);
    xa0.s[2] = f2bf(XF0a.z); xa0.s[3] = f2bf(XF0a.w);
    xa0.s[4] = f2bf(XF0b.x); xa0.s[5] = f2bf(XF0b.y);
    xa0.s[6] = f2bf(XF0b.z); xa0.s[7] = f2bf(XF0b.w);
    xa1.s[0] = f2bf(XF1a.x); xa1.s[1] = f2bf(XF1a.y);
    xa1.s[2] = f2bf(XF1a.z); xa1.s[3] = f2bf(XF1a.w);
    xa1.s[4] = f2bf(XF1b.x); xa1.s[5] = f2bf(XF1b.y);
    xa1.s[6] = f2bf(XF1b.z); xa1.s[7] = f2bf(XF1b.w);
    // 12 MFMA
    f32x4 zz = {0.f, 0.f, 0.f, 0.f};
    f32x4 aR = MFMA16(xa0.v, BXr0, zz); aR = MFMA16(xa1.v, BXr1, aR);
    aR = MFMA16(HA0, BHr0, aR);         aR = MFMA16(HA1, BHr1, aR);
    f32x4 aZ = MFMA16(xa0.v, BXz0, zz); aZ = MFMA16(xa1.v, BXz1, aZ);
    aZ = MFMA16(HA0, BHz0, aZ);         aZ = MFMA16(HA1, BHz1, aZ);
    f32x4 aNX = MFMA16(xa0.v, BXn0, zz); aNX = MFMA16(xa1.v, BXn1, aNX);
    f32x4 aNH = MFMA16(HA0, BHn0, zz);   aNH = MFMA16(HA1, BHn1, aNH);
    // prefetch X(t+1) fp32 (4 loads)
    const int tn = (t + 1 < 512) ? t + 1 : 511;
    XF0a = LD4(xarow + tn * 64 + kg * 8);
    XF0b = LD4(xarow + tn * 64 + kg * 8 + 4);
    XF1a = LD4(xarow + tn * 64 + 32 + kg * 8);
    XF1b = LD4(xarow + tn * 64 + 32 + kg * 8 + 4);
    // prefetch delta(t+1) (12 clamped loads)
    float ndR[4], ndZ[4], ndN[4];
    int nmsk[4];
#pragma unroll
    for (int i = 0; i < 4; ++i) {
      const int idx = idxl[4 * kg + i][tn];
      nmsk[i] = (idx >= 0);
      const float* dp = delta_gi + (int64_t)(idx < 0 ? 0 : idx) * 192;
      ndR[i] = dp[u]; ndZ[i] = dp[64 + u]; ndN[i] = dp[128 + u];
    }
    // activations + h update + writes (delta(t) from regs)
    unsigned short* hwb = (unsigned short*)h_lds[t & 1];
#pragma unroll
    for (int i = 0; i < 4; ++i) {
      const float ddR = msk[i] ? dR[i] : 0.f;
      const float ddZ = msk[i] ? dZ[i] : 0.f;
      const float ddN = msk[i] ? dN[i] : 0.f;
      const float r = fsig_(aR[i] + brz_r + ddR);
      const float zg = fsig_(aZ[i] + brz_z + ddZ);
      const float nn = ftanh_(aNX[i] + bin + ddN + r * (aNH[i] + bhn));
      const float hn = (1.f - zg) * nn + zg * ho[i];
      ho[i] = hn;
      const int row = 4 * kg + i;
      *(unsigned short*)((char*)hwb + row * 144 + u * 2) = f2bf(hn);
      x[(int64_t)(b0 + row) * 32768 + t * 64 + u] = hn;
    }
#pragma unroll
    for (int i = 0; i < 4; ++i) {
      dR[i] = ndR[i]; dZ[i] = ndZ[i]; dN[i] = ndN[i]; msk[i] = nmsk[i];
    }
    // Retire everything except {12 delta(t+1) + 4 stores}: x(t+1) lands
    // before the barrier -> no RAW race with next step's in-place stores.
    asm volatile("s_waitcnt vmcnt(16)" ::: "memory");
    barrier_lgkm();  // h(t) published (single barrier per step)
  }
}

// One block per (path, direction). 7-step GRU, D=68, gates 204.
// graph_emb computed inline from col_sum.
__global__ __launch_bounds__(256) void path_kernel(
    const float* __restrict__ x, const int* __restrict__ paths,
    const float* __restrict__ demands, const float* __restrict__ wd,
    const float* __restrict__ col_sum,
    const float* __restrict__ wih_f, const float* __restrict__ whh_f,
    const float* __restrict__ bih_f, const float* __restrict__ bhh_f,
    const float* __restrict__ wih_b, const float* __restrict__ whh_b,
    const float* __restrict__ bih_b, const float* __restrict__ bhh_b,
    float* __restrict__ h_out)
{
  const int p = blockIdx.x & 63;
  const int dir = blockIdx.x >> 6;
  const int g = threadIdx.x;
  const float* w_ih = dir ? wih_b : wih_f;
  const float* w_hh = dir ? whh_b : whh_f;
  const float* bih = dir ? bih_b : bih_f;
  const float* bhh = dir ? bhh_b : bhh_f;
  __shared__ float feat[7][68], hs[68], rbuf[68], zbuf[68];
  if (g < 64) {
    float s = 0.f;
#pragma unroll 8
    for (int jj = 0; jj < 512; ++jj) s += col_sum[jj * 64 + g];
    hs[g] = s * (1.f / 262144.f);
  } else if (g < 68) {
    hs[g] = 0.f;
  }
  if (g < 68) {
#pragma unroll
    for (int t = 0; t < 7; ++t) {
      const int src = paths[p * 8 + t];
      const int dst = paths[p * 8 + t + 1];
      feat[t][g] = (g < 64) ? x[((int64_t)src * 512 + dst) * 64 + g]
                            : fmaxf(demands[p] * wd[g - 64], 0.f);
    }
  }
  __syncthreads();
  for (int s = 0; s < 7; ++s) {
    const int t = dir ? (6 - s) : s;
    float acc = 0.f, hacc = 0.f;
    if (g < 204) {
      acc = bih[g];
      hacc = bhh[g];
      for (int k = 0; k < 68; ++k) {
        acc += feat[t][k] * w_ih[g * 68 + k];
        hacc += hs[k] * w_hh[g * 68 + k];
      }
    }
    if (g < 68) rbuf[g] = sig_(acc + hacc);
    else if (g < 136) zbuf[g - 68] = sig_(acc + hacc);
    __syncthreads();
    if (g >= 136 && g < 204) {
      const int j = g - 136;
      const float n = tanhf(acc + rbuf[j] * hacc);
      const float z = zbuf[j];
      const float hn = (1.f - z) * n + z * hs[j];
      hs[j] = hn;
    }
    __syncthreads();
  }
  if (g < 68) h_out[(dir * 64 + p) * 68 + g] = hs[g];
}

__global__ __launch_bounds__(64) void combine_kernel(
    const float* __restrict__ h_out, const float* __restrict__ wq,
    const float* __restrict__ bq, float* __restrict__ out)
{
  const int p = threadIdx.x;
  float l = bq[0];
#pragma unroll
  for (int d = 0; d < 68; ++d)
    l += 0.5f * (h_out[p * 68 + d] + h_out[(64 + p) * 68 + d]) * wq[d];
  float mx = l;
#pragma unroll
  for (int off = 32; off > 0; off >>= 1) mx = fmaxf(mx, __shfl_xor(mx, off, 64));
  const float e = expf(l - mx);
  float s = e;
#pragma unroll
  for (int off = 32; off > 0; off >>= 1) s += __shfl_xor(s, off, 64);
  out[p] = e / s;
}

extern "C" void kernel_launch(void* const* d_in, const int* in_sizes, int n_in,
                              void* d_out, int out_size, void* d_ws, size_t ws_size,
                              hipStream_t stream)
{
  const float* adj = (const float*)d_in[0];
  const int* edges = (const int*)d_in[1];
  const int* paths = (const int*)d_in[2];
  const float* demands = (const float*)d_in[3];
  const float* emb_w = (const float*)d_in[4];
  const float* w1s = (const float*)d_in[5];
  const float* w2s = (const float*)d_in[6];
  const float* w3s = (const float*)d_in[7];
  const float* gru_w_ih = (const float*)d_in[8];
  const float* gru_w_hh = (const float*)d_in[9];
  const float* gru_b_ih = (const float*)d_in[10];
  const float* gru_b_hh = (const float*)d_in[11];
  const float* pf_w_ih = (const float*)d_in[12];
  const float* pf_w_hh = (const float*)d_in[13];
  const float* pf_b_ih = (const float*)d_in[14];
  const float* pf_b_hh = (const float*)d_in[15];
  const float* pb_w_ih = (const float*)d_in[16];
  const float* pb_w_hh = (const float*)d_in[17];
  const float* pb_b_ih = (const float*)d_in[18];
  const float* pb_b_hh = (const float*)d_in[19];
  const float* wq = (const float*)d_in[20];
  const float* bq = (const float*)d_in[21];
  const float* wd = (const float*)d_in[22];
  float* out = (float*)d_out;

  // Workspace layout (floats): ~74.6 MB total (known-safe size)
  float* xA = (float*)d_ws;                    // 512*512*64 = 16777216
  float* col_sum = xA + 16777216;              // 32768
  int* col_nz = (int*)(col_sum + 32768);       // 512
  int* idxmap = col_nz + 512;                  // 262144
  float* delta_gi = (float*)(idxmap + 262144); // 8192*192 = 1572864
  float* h_out = delta_gi + 1572864;           // 2*64*68 = 8704

  hipMemsetAsync(idxmap, 0xFF, 262144 * sizeof(int), stream);
  scatter_idx_kernel<<<32, 256, 0, stream>>>(edges, idxmap);
  embed_kernel<<<65536, 256, 0, stream>>>(adj, emb_w, xA);

  for (int t = 0; t < 3; ++t) {
    colsum_kernel<<<512, 256, 0, stream>>>(xA, col_sum, col_nz);
    edge_kernel<<<2048, 256, 0, stream>>>(xA, edges, col_sum, col_nz,
        w1s + t * 4096, w2s + t * 4096, w3s + t * 4096, gru_w_ih, delta_gi);
    scan_mfma_kernel<<<32, 256, 0, stream>>>(xA, delta_gi, idxmap,
        gru_w_ih, gru_w_hh, gru_b_ih, gru_b_hh);
  }

  colsum_kernel<<<512, 256, 0, stream>>>(xA, col_sum, col_nz);
  path_kernel<<<128, 256, 0, stream>>>(xA, paths, demands, wd, col_sum,
      pf_w_ih, pf_w_hh, pf_b_ih, pf_b_hh,
      pb_w_ih, pb_w_hh, pb_b_ih, pb_b_hh, h_out);
  combine_kernel<<<1, 64, 0, stream>>>(h_out, wq, bq, out);
}

// Round 19
// 1968.906 us; speedup vs baseline: 1.2366x; 1.1821x over previous
//
#include <hip/hip_runtime.h>

// Sizes (fixed): V=512, F_IN=8, H=64, DH=4, T=3, E=8192, P=64, L=8, D=68

__device__ __forceinline__ float fsig_(float x) { return 1.f / (1.f + __expf(-x)); }
__device__ __forceinline__ float ftanh_(float x) {
  float e = __expf(2.f * x);
  return 1.f - 2.f / (e + 1.f);
}
__device__ __forceinline__ float sig_(float x) { return 1.f / (1.f + expf(-x)); }

// f32 -> bf16 (round-to-nearest-even) and back.
__device__ __forceinline__ unsigned short f2bf(float f) {
  union { float f; unsigned u; } a; a.f = f;
  unsigned r = a.u + 0x7FFFu + ((a.u >> 16) & 1u);
  return (unsigned short)(r >> 16);
}
__device__ __forceinline__ float bf2f(unsigned short s) {
  union { unsigned u; float f; } a; a.u = ((unsigned)s) << 16;
  return a.f;
}

// Barrier WITHOUT vmcnt drain: LDS ordering only.
__device__ __forceinline__ void barrier_lgkm() {
  asm volatile("s_waitcnt lgkmcnt(0)\n\ts_barrier" ::: "memory");
}

// NOTE: macro params must NOT collide with float4 member names (x/y/z/w).
#define LD4(p) (*(const float4*)(p))
#define DOT4(acc, va, vb)                                                      \
  do {                                                                         \
    acc += (va).x * (vb).x; acc += (va).y * (vb).y;                            \
    acc += (va).z * (vb).z; acc += (va).w * (vb).w;                            \
  } while (0)

#define ALL16(M) M(0) M(1) M(2) M(3) M(4) M(5) M(6) M(7)                       \
                 M(8) M(9) M(10) M(11) M(12) M(13) M(14) M(15)
#define ALLQ(M) M(0,0) M(1,1) M(2,2) M(3,3) M(4,0) M(5,1) M(6,2) M(7,3)        \
                M(8,0) M(9,1) M(10,2) M(11,3) M(12,0) M(13,1) M(14,2) M(15,3)

// x[i,j,h] = sum_f adj[i,j,f] * emb[h,f]
__global__ __launch_bounds__(256) void embed_kernel(
    const float* __restrict__ adj, const float* __restrict__ emb,
    float* __restrict__ x)
{
  const int64_t row = (int64_t)blockIdx.x * 4 + (threadIdx.x >> 6);
  const int h = threadIdx.x & 63;
  const float* a = adj + row * 8;
  float acc = 0.f;
#pragma unroll
  for (int f = 0; f < 8; ++f) acc += a[f] * emb[h * 8 + f];
  x[row * 64 + h] = acc;
}

// col_sum[j,h] = sum_i x[i,j,h];  col_nz[j] = sum_i sum_h (x[i,j,h]!=0)
__global__ __launch_bounds__(256) void colsum_kernel(
    const float* __restrict__ x, float* __restrict__ col_sum,
    int* __restrict__ col_nz)
{
  const int j = blockIdx.x;
  const int h = threadIdx.x & 63;
  const int w = threadIdx.x >> 6;
  float acc = 0.f;
  int nz = 0;
  for (int i = w; i < 512; i += 4) {
    float v = x[((int64_t)i * 512 + j) * 64 + h];
    acc += v;
    nz += (v != 0.f) ? 1 : 0;
  }
  __shared__ float pacc[4][64];
  __shared__ int pnz[4];
#pragma unroll
  for (int off = 32; off > 0; off >>= 1) nz += __shfl_down(nz, off, 64);
  if (h == 0) pnz[w] = nz;
  pacc[w][h] = acc;
  __syncthreads();
  if (w == 0) {
    col_sum[j * 64 + h] = pacc[0][h] + pacc[1][h] + pacc[2][h] + pacc[3][h];
    if (h == 0) col_nz[j] = pnz[0] + pnz[1] + pnz[2] + pnz[3];
  }
}

__global__ void scatter_idx_kernel(const int* __restrict__ edges,
                                   int* __restrict__ idxmap)
{
  const int e = blockIdx.x * 256 + threadIdx.x;
  if (e < 8192) idxmap[edges[e * 2] * 512 + edges[e * 2 + 1]] = e;
}

// Pre-convert scan weights to bf16 in workspace:
//   wsum_bf[g][k] = bf16(w_ih[g][k] + w_ih[g][64+k]),  whh_bf[g][k] = bf16(w_hh[g][k])
// Halves (producer: quarters) the per-step L2 weight-stream bytes that the
// allocator's remat policy forces (r18 analysis: scan is L2-BW bound).
__global__ __launch_bounds__(256) void prep_weights_kernel(
    const float* __restrict__ w_ih, const float* __restrict__ w_hh,
    unsigned short* __restrict__ wsum_bf, unsigned short* __restrict__ whh_bf)
{
  for (int i = threadIdx.x; i < 12288; i += 256) {
    const int g = i >> 6, k = i & 63;
    wsum_bf[i] = f2bf(w_ih[g * 128 + k] + w_ih[g * 128 + 64 + k]);
    whh_bf[i] = f2bf(w_hh[i]);
  }
}

// Per-edge message m_e, then delta_gi[e,g] = sum_h (m_e[h]-x_uv[h]) * w_ih[g,h]
// 4 edges per block, one 64-lane wave each (ballot/popc are per-wave).
__global__ __launch_bounds__(256) void edge_kernel(
    const float* __restrict__ x, const int* __restrict__ edges,
    const float* __restrict__ col_sum, const int* __restrict__ col_nz,
    const float* __restrict__ w1, const float* __restrict__ w2,
    const float* __restrict__ w3, const float* __restrict__ w_ih,
    float* __restrict__ delta_gi)
{
  const int wv = threadIdx.x >> 6;
  const int e = blockIdx.x * 4 + wv;
  const int h = threadIdx.x & 63;
  const int u = edges[e * 2 + 0];
  const int v = edges[e * 2 + 1];
  __shared__ __align__(16) float xuv[4][64], ein[4][64], eout[4][64], dm[4][64];
  const float xuvh = x[((int64_t)u * 512 + v) * 64 + h];
  const float xvuh = x[((int64_t)v * 512 + u) * 64 + h];
  xuv[wv][h] = xuvh;
  const int nz_vu = __popcll(__ballot(xvuh != 0.f));
  const int nz_uv = __popcll(__ballot(xuvh != 0.f));
  float n_in = (float)(col_nz[u] - nz_vu) / 64.f;
  if (n_in == 0.f) n_in = 1.f;
  float n_out = (float)(col_nz[v] - nz_uv) / 64.f;
  if (n_out == 0.f) n_out = 1.f;
  ein[wv][h] = (col_sum[u * 64 + h] - xvuh) / n_in;
  eout[wv][h] = (col_sum[v * 64 + h] - xuvh) / n_out;
  __syncthreads();
  const float4* w1r = (const float4*)(w1 + h * 64);
  const float4* w2r = (const float4*)(w2 + h * 64);
  const float4* w3r = (const float4*)(w3 + h * 64);
  const float4* xuv4 = (const float4*)&xuv[wv][0];
  const float4* ein4 = (const float4*)&ein[wv][0];
  const float4* eout4 = (const float4*)&eout[wv][0];
  float acc = 0.f;
#pragma unroll
  for (int kk = 0; kk < 16; ++kk) {
    float4 a = xuv4[kk], b = w1r[kk];
    acc += a.x * b.x + a.y * b.y + a.z * b.z + a.w * b.w;
    a = ein4[kk]; b = w2r[kk];
    acc += a.x * b.x + a.y * b.y + a.z * b.z + a.w * b.w;
    a = eout4[kk]; b = w3r[kk];
    acc += a.x * b.x + a.y * b.y + a.z * b.z + a.w * b.w;
  }
  const float m = fmaxf(acc, 0.f);
  dm[wv][h] = m - xuvh;
  __syncthreads();
  const float4* dm4 = (const float4*)&dm[wv][0];
#pragma unroll
  for (int r = 0; r < 3; ++r) {
    const int gg = h + r * 64;
    const float4* wr = (const float4*)(w_ih + gg * 128);
    float d = 0.f;
#pragma unroll
    for (int kk = 0; kk < 16; ++kk) {
      float4 a = dm4[kk], b = wr[kk];
      d += a.x * b.x + a.y * b.y + a.z * b.z + a.w * b.w;
    }
    delta_gi[e * 192 + gg] = d;
  }
}

// ---- GRU scan v14: v4 structure (best, 497us) + bf16 weight stream. ----
// 256 thr = 4 waves, one row per block, grid 512 (2 blocks/CU).
// The allocator remats weight loads from cache every step (r8-r15: pinning
// impossible); r18 arithmetic shows the scan is L2-BW bound on those bytes.
// Weights now stream as bf16 (8B/quartet vs 16-32B) -> 3x fewer bytes.
#define DECL_W(i)                                                              \
  float4 W##i; {                                                               \
    ushort4 tb = *(const ushort4*)(wgb + 4 * (i));                             \
    W##i.x = bf2f(tb.x); W##i.y = bf2f(tb.y);                                  \
    W##i.z = bf2f(tb.z); W##i.w = bf2f(tb.w);                                  \
  }
#define DECL_X(i) float4 X##i = LD4(xrow + 4 * (i));
#define PQ(i, q) { DOT4(ac##q, X##i, W##i); X##i = LD4(xnext + 4 * (i)); }
#define DECL_WR(i)                                                             \
  float4 WR##i; {                                                              \
    ushort4 tb = *(const ushort4*)(wr_ + 4 * (i));                             \
    WR##i.x = bf2f(tb.x); WR##i.y = bf2f(tb.y);                                \
    WR##i.z = bf2f(tb.z); WR##i.w = bf2f(tb.w);                                \
  }
#define DECL_WZ(i)                                                             \
  float4 WZ##i; {                                                              \
    ushort4 tb = *(const ushort4*)(wz_ + 4 * (i));                             \
    WZ##i.x = bf2f(tb.x); WZ##i.y = bf2f(tb.y);                                \
    WZ##i.z = bf2f(tb.z); WZ##i.w = bf2f(tb.w);                                \
  }
#define DECL_WN(i)                                                             \
  float4 WN##i; {                                                              \
    ushort4 tb = *(const ushort4*)(wn_ + 4 * (i));                             \
    WN##i.x = bf2f(tb.x); WN##i.y = bf2f(tb.y);                                \
    WN##i.z = bf2f(tb.z); WN##i.w = bf2f(tb.w);                                \
  }
#define CCHUNK(i)                                                              \
  { float4 hc = hs4[(i)];                                                      \
    DOT4(racc, hc, WR##i); DOT4(zacc, hc, WZ##i); DOT4(nacc, hc, WN##i); }

__global__ __launch_bounds__(256, 2) void scan_kernel(
    float* __restrict__ x, const float* __restrict__ delta_gi,
    const int* __restrict__ idxmap,
    const unsigned short* __restrict__ wsum_bf,
    const unsigned short* __restrict__ whh_bf,
    const float* __restrict__ b_ih, const float* __restrict__ b_hh)
{
  const int b = blockIdx.x;
  const int tid = threadIdx.x;
  __shared__ __align__(16) float hs[64];
  __shared__ float gib[2][192];
  __shared__ int idxl[512];
  float* xrow = x + (int64_t)b * 32768;

  for (int i = tid; i < 512; i += 256) idxl[i] = idxmap[b * 512 + i];

  if (tid < 192) {
    // ---------------- producer ----------------
    const int g = tid;
    const unsigned short* wgb = wsum_bf + g * 64;
    ALL16(DECL_W)
    const float bi = b_ih[g];
    ALL16(DECL_X)          // X = x[0]
    __syncthreads();       // idxl staged, hs inited
    {                      // prologue: gib[0] (and reload X <- x[1])
      float ac0 = bi, ac1 = 0.f, ac2 = 0.f, ac3 = 0.f;
      const float* xnext = xrow + 64;
      ALLQ(PQ)
      float acc = (ac0 + ac1) + (ac2 + ac3);
      const int i0 = idxl[0];
      if (i0 >= 0) acc += delta_gi[(int64_t)i0 * 192 + g];
      gib[0][g] = acc;
    }
    const int idx1 = idxl[1];
    float dgn = 0.f;
    if (idx1 >= 0) dgn = delta_gi[(int64_t)idx1 * 192 + g];
    barrier_lgkm();        // gib[0] published
    for (int t = 0; t < 512; ++t) {
      if (t < 511) {
        const int tn2 = (t + 2 < 512) ? (t + 2) : 511;
        const float* xnext = xrow + tn2 * 64;
        float ac0 = bi + dgn, ac1 = 0.f, ac2 = 0.f, ac3 = 0.f;
        ALLQ(PQ)           // consumes X = x[t+1], reloads X <- x[tn2]
        gib[(t + 1) & 1][g] = (ac0 + ac1) + (ac2 + ac3);
        const int idxn = idxl[tn2];
        dgn = 0.f;
        if (idxn >= 0) dgn = delta_gi[(int64_t)idxn * 192 + g];
      }
      barrier_lgkm();      // gib[t+1] published / h(t) published
    }
  } else {
    // ---------------- consumer ----------------
    const int j = tid - 192;
    const unsigned short* wr_ = whh_bf + j * 64;
    const unsigned short* wz_ = whh_bf + (j + 64) * 64;
    const unsigned short* wn_ = whh_bf + (j + 128) * 64;
    ALL16(DECL_WR)
    ALL16(DECL_WZ)
    ALL16(DECL_WN)
    const float bhr = b_hh[j], bhz = b_hh[j + 64], bhn = b_hh[j + 128];
    float hj = 0.f;
    hs[j] = 0.f;
    __syncthreads();
    __builtin_amdgcn_s_setprio(1);  // consumer wave is the critical path
    barrier_lgkm();
    const float4* hs4 = (const float4*)hs;
    for (int t = 0; t < 512; ++t) {
      const float gr = gib[t & 1][j];
      const float gz = gib[t & 1][64 + j];
      const float gn = gib[t & 1][128 + j];
      float racc = bhr, zacc = bhz, nacc = bhn;
      ALL16(CCHUNK)
      const float r = fsig_(gr + racc);
      const float z = fsig_(gz + zacc);
      const float n = ftanh_(gn + r * nacc);
      hj = (1.f - z) * n + z * hj;
      hs[j] = hj;
      xrow[t * 64 + j] = hj;
      barrier_lgkm();      // h(t) published / next gib published
    }
  }
}

// One block per (path, direction). 7-step GRU, D=68, gates 204.
// graph_emb computed inline from col_sum.
__global__ __launch_bounds__(256) void path_kernel(
    const float* __restrict__ x, const int* __restrict__ paths,
    const float* __restrict__ demands, const float* __restrict__ wd,
    const float* __restrict__ col_sum,
    const float* __restrict__ wih_f, const float* __restrict__ whh_f,
    const float* __restrict__ bih_f, const float* __restrict__ bhh_f,
    const float* __restrict__ wih_b, const float* __restrict__ whh_b,
    const float* __restrict__ bih_b, const float* __restrict__ bhh_b,
    float* __restrict__ h_out)
{
  const int p = blockIdx.x & 63;
  const int dir = blockIdx.x >> 6;
  const int g = threadIdx.x;
  const float* w_ih = dir ? wih_b : wih_f;
  const float* w_hh = dir ? whh_b : whh_f;
  const float* bih = dir ? bih_b : bih_f;
  const float* bhh = dir ? bhh_b : bhh_f;
  __shared__ float feat[7][68], hs[68], rbuf[68], zbuf[68];
  if (g < 64) {
    float s = 0.f;
#pragma unroll 8
    for (int jj = 0; jj < 512; ++jj) s += col_sum[jj * 64 + g];
    hs[g] = s * (1.f / 262144.f);
  } else if (g < 68) {
    hs[g] = 0.f;
  }
  if (g < 68) {
#pragma unroll
    for (int t = 0; t < 7; ++t) {
      const int src = paths[p * 8 + t];
      const int dst = paths[p * 8 + t + 1];
      feat[t][g] = (g < 64) ? x[((int64_t)src * 512 + dst) * 64 + g]
                            : fmaxf(demands[p] * wd[g - 64], 0.f);
    }
  }
  __syncthreads();
  for (int s = 0; s < 7; ++s) {
    const int t = dir ? (6 - s) : s;
    float acc = 0.f, hacc = 0.f;
    if (g < 204) {
      acc = bih[g];
      hacc = bhh[g];
      for (int k = 0; k < 68; ++k) {
        acc += feat[t][k] * w_ih[g * 68 + k];
        hacc += hs[k] * w_hh[g * 68 + k];
      }
    }
    if (g < 68) rbuf[g] = sig_(acc + hacc);
    else if (g < 136) zbuf[g - 68] = sig_(acc + hacc);
    __syncthreads();
    if (g >= 136 && g < 204) {
      const int j = g - 136;
      const float n = tanhf(acc + rbuf[j] * hacc);
      const float z = zbuf[j];
      const float hn = (1.f - z) * n + z * hs[j];
      hs[j] = hn;
    }
    __syncthreads();
  }
  if (g < 68) h_out[(dir * 64 + p) * 68 + g] = hs[g];
}

__global__ __launch_bounds__(64) void combine_kernel(
    const float* __restrict__ h_out, const float* __restrict__ wq,
    const float* __restrict__ bq, float* __restrict__ out)
{
  const int p = threadIdx.x;
  float l = bq[0];
#pragma unroll
  for (int d = 0; d < 68; ++d)
    l += 0.5f * (h_out[p * 68 + d] + h_out[(64 + p) * 68 + d]) * wq[d];
  float mx = l;
#pragma unroll
  for (int off = 32; off > 0; off >>= 1) mx = fmaxf(mx, __shfl_xor(mx, off, 64));
  const float e = expf(l - mx);
  float s = e;
#pragma unroll
  for (int off = 32; off > 0; off >>= 1) s += __shfl_xor(s, off, 64);
  out[p] = e / s;
}

extern "C" void kernel_launch(void* const* d_in, const int* in_sizes, int n_in,
                              void* d_out, int out_size, void* d_ws, size_t ws_size,
                              hipStream_t stream)
{
  const float* adj = (const float*)d_in[0];
  const int* edges = (const int*)d_in[1];
  const int* paths = (const int*)d_in[2];
  const float* demands = (const float*)d_in[3];
  const float* emb_w = (const float*)d_in[4];
  const float* w1s = (const float*)d_in[5];
  const float* w2s = (const float*)d_in[6];
  const float* w3s = (const float*)d_in[7];
  const float* gru_w_ih = (const float*)d_in[8];
  const float* gru_w_hh = (const float*)d_in[9];
  const float* gru_b_ih = (const float*)d_in[10];
  const float* gru_b_hh = (const float*)d_in[11];
  const float* pf_w_ih = (const float*)d_in[12];
  const float* pf_w_hh = (const float*)d_in[13];
  const float* pf_b_ih = (const float*)d_in[14];
  const float* pf_b_hh = (const float*)d_in[15];
  const float* pb_w_ih = (const float*)d_in[16];
  const float* pb_w_hh = (const float*)d_in[17];
  const float* pb_b_ih = (const float*)d_in[18];
  const float* pb_b_hh = (const float*)d_in[19];
  const float* wq = (const float*)d_in[20];
  const float* bq = (const float*)d_in[21];
  const float* wd = (const float*)d_in[22];
  float* out = (float*)d_out;

  // Workspace layout (floats): ~74.7 MB total (known-safe size)
  float* xA = (float*)d_ws;                    // 512*512*64 = 16777216
  float* col_sum = xA + 16777216;              // 32768
  int* col_nz = (int*)(col_sum + 32768);       // 512
  int* idxmap = col_nz + 512;                  // 262144
  float* delta_gi = (float*)(idxmap + 262144); // 8192*192 = 1572864
  float* h_out = delta_gi + 1572864;           // 8704
  unsigned short* wsum_bf = (unsigned short*)(h_out + 8704);  // 12288 shorts
  unsigned short* whh_bf = wsum_bf + 12288;                   // 12288 shorts

  hipMemsetAsync(idxmap, 0xFF, 262144 * sizeof(int), stream);
  scatter_idx_kernel<<<32, 256, 0, stream>>>(edges, idxmap);
  prep_weights_kernel<<<1, 256, 0, stream>>>(gru_w_ih, gru_w_hh,
                                             wsum_bf, whh_bf);
  embed_kernel<<<65536, 256, 0, stream>>>(adj, emb_w, xA);

  for (int t = 0; t < 3; ++t) {
    colsum_kernel<<<512, 256, 0, stream>>>(xA, col_sum, col_nz);
    edge_kernel<<<2048, 256, 0, stream>>>(xA, edges, col_sum, col_nz,
        w1s + t * 4096, w2s + t * 4096, w3s + t * 4096, gru_w_ih, delta_gi);
    scan_kernel<<<512, 256, 0, stream>>>(xA, delta_gi, idxmap,
        wsum_bf, whh_bf, gru_b_ih, gru_b_hh);
  }

  colsum_kernel<<<512, 256, 0, stream>>>(xA, col_sum, col_nz);
  path_kernel<<<128, 256, 0, stream>>>(xA, paths, demands, wd, col_sum,
      pf_w_ih, pf_w_hh, pf_b_ih, pf_b_hh,
      pb_w_ih, pb_w_hh, pb_b_ih, pb_b_hh, h_out);
  combine_kernel<<<1, 64, 0, stream>>>(h_out, wq, bq, out);
}

// Round 20
// 1860.868 us; speedup vs baseline: 1.3084x; 1.0581x over previous
//
#include <hip/hip_runtime.h>

// Sizes (fixed): V=512, F_IN=8, H=64, DH=4, T=3, E=8192, P=64, L=8, D=68

__device__ __forceinline__ float fsig_(float x) { return 1.f / (1.f + __expf(-x)); }
__device__ __forceinline__ float ftanh_(float x) {
  float e = __expf(2.f * x);
  return 1.f - 2.f / (e + 1.f);
}
__device__ __forceinline__ float sig_(float x) { return 1.f / (1.f + expf(-x)); }

// Barrier WITHOUT vmcnt drain: LDS ordering only.
__device__ __forceinline__ void barrier_lgkm() {
  asm volatile("s_waitcnt lgkmcnt(0)\n\ts_barrier" ::: "memory");
}

// Pin a float4 into VGPRs (opaque redefinition at the asm site).
#define PIN4(v) asm volatile("" : "+v"((v).x), "+v"((v).y), "+v"((v).z), "+v"((v).w))

// NOTE: macro params must NOT collide with float4 member names (x/y/z/w).
#define LD4(p) (*(const float4*)(p))
#define DOT4(acc, va, vb)                                                      \
  do {                                                                         \
    acc += (va).x * (vb).x; acc += (va).y * (vb).y;                            \
    acc += (va).z * (vb).z; acc += (va).w * (vb).w;                            \
  } while (0)

#define ALL16(M) M(0) M(1) M(2) M(3) M(4) M(5) M(6) M(7)                       \
                 M(8) M(9) M(10) M(11) M(12) M(13) M(14) M(15)
#define ALLQ(M) M(0,0) M(1,1) M(2,2) M(3,3) M(4,0) M(5,1) M(6,2) M(7,3)        \
                M(8,0) M(9,1) M(10,2) M(11,3) M(12,0) M(13,1) M(14,2) M(15,3)

// x[i,j,h] = sum_f adj[i,j,f] * emb[h,f]
__global__ __launch_bounds__(256) void embed_kernel(
    const float* __restrict__ adj, const float* __restrict__ emb,
    float* __restrict__ x)
{
  const int64_t row = (int64_t)blockIdx.x * 4 + (threadIdx.x >> 6);
  const int h = threadIdx.x & 63;
  const float* a = adj + row * 8;
  float acc = 0.f;
#pragma unroll
  for (int f = 0; f < 8; ++f) acc += a[f] * emb[h * 8 + f];
  x[row * 64 + h] = acc;
}

// col_sum[j,h] = sum_i x[i,j,h];  col_nz[j] = sum_i sum_h (x[i,j,h]!=0)
__global__ __launch_bounds__(256) void colsum_kernel(
    const float* __restrict__ x, float* __restrict__ col_sum,
    int* __restrict__ col_nz)
{
  const int j = blockIdx.x;
  const int h = threadIdx.x & 63;
  const int w = threadIdx.x >> 6;
  float acc = 0.f;
  int nz = 0;
  for (int i = w; i < 512; i += 4) {
    float v = x[((int64_t)i * 512 + j) * 64 + h];
    acc += v;
    nz += (v != 0.f) ? 1 : 0;
  }
  __shared__ float pacc[4][64];
  __shared__ int pnz[4];
#pragma unroll
  for (int off = 32; off > 0; off >>= 1) nz += __shfl_down(nz, off, 64);
  if (h == 0) pnz[w] = nz;
  pacc[w][h] = acc;
  __syncthreads();
  if (w == 0) {
    col_sum[j * 64 + h] = pacc[0][h] + pacc[1][h] + pacc[2][h] + pacc[3][h];
    if (h == 0) col_nz[j] = pnz[0] + pnz[1] + pnz[2] + pnz[3];
  }
}

__global__ void scatter_idx_kernel(const int* __restrict__ edges,
                                   int* __restrict__ idxmap)
{
  const int e = blockIdx.x * 256 + threadIdx.x;
  if (e < 8192) idxmap[edges[e * 2] * 512 + edges[e * 2 + 1]] = e;
}

// Per-edge message m_e, then delta_gi[e,g] = sum_h (m_e[h]-x_uv[h]) * w_ih[g,h]
// 4 edges per block, one 64-lane wave each (ballot/popc are per-wave).
__global__ __launch_bounds__(256) void edge_kernel(
    const float* __restrict__ x, const int* __restrict__ edges,
    const float* __restrict__ col_sum, const int* __restrict__ col_nz,
    const float* __restrict__ w1, const float* __restrict__ w2,
    const float* __restrict__ w3, const float* __restrict__ w_ih,
    float* __restrict__ delta_gi)
{
  const int wv = threadIdx.x >> 6;
  const int e = blockIdx.x * 4 + wv;
  const int h = threadIdx.x & 63;
  const int u = edges[e * 2 + 0];
  const int v = edges[e * 2 + 1];
  __shared__ __align__(16) float xuv[4][64], ein[4][64], eout[4][64], dm[4][64];
  const float xuvh = x[((int64_t)u * 512 + v) * 64 + h];
  const float xvuh = x[((int64_t)v * 512 + u) * 64 + h];
  xuv[wv][h] = xuvh;
  const int nz_vu = __popcll(__ballot(xvuh != 0.f));
  const int nz_uv = __popcll(__ballot(xuvh != 0.f));
  float n_in = (float)(col_nz[u] - nz_vu) / 64.f;
  if (n_in == 0.f) n_in = 1.f;
  float n_out = (float)(col_nz[v] - nz_uv) / 64.f;
  if (n_out == 0.f) n_out = 1.f;
  ein[wv][h] = (col_sum[u * 64 + h] - xvuh) / n_in;
  eout[wv][h] = (col_sum[v * 64 + h] - xuvh) / n_out;
  __syncthreads();
  const float4* w1r = (const float4*)(w1 + h * 64);
  const float4* w2r = (const float4*)(w2 + h * 64);
  const float4* w3r = (const float4*)(w3 + h * 64);
  const float4* xuv4 = (const float4*)&xuv[wv][0];
  const float4* ein4 = (const float4*)&ein[wv][0];
  const float4* eout4 = (const float4*)&eout[wv][0];
  float acc = 0.f;
#pragma unroll
  for (int kk = 0; kk < 16; ++kk) {
    float4 a = xuv4[kk], b = w1r[kk];
    acc += a.x * b.x + a.y * b.y + a.z * b.z + a.w * b.w;
    a = ein4[kk]; b = w2r[kk];
    acc += a.x * b.x + a.y * b.y + a.z * b.z + a.w * b.w;
    a = eout4[kk]; b = w3r[kk];
    acc += a.x * b.x + a.y * b.y + a.z * b.z + a.w * b.w;
  }
  const float m = fmaxf(acc, 0.f);
  dm[wv][h] = m - xuvh;
  __syncthreads();
  const float4* dm4 = (const float4*)&dm[wv][0];
#pragma unroll
  for (int r = 0; r < 3; ++r) {
    const int gg = h + r * 64;
    const float4* wr = (const float4*)(w_ih + gg * 128);
    float d = 0.f;
#pragma unroll
    for (int kk = 0; kk < 16; ++kk) {
      float4 a = dm4[kk], b = wr[kk];
      d += a.x * b.x + a.y * b.y + a.z * b.z + a.w * b.w;
    }
    delta_gi[e * 192 + gg] = d;
  }
}

// ---- GRU scan (r8's v4 — measured best, ~500 us/layer). ----
// 256 thr = 4 waves, one row per block. Waves 0-2 (producers): gate g = tid,
// wsum in 16 float4; x[t+1] prefetched in named regs via use-then-reload.
// Wave 3 (consumer): whh rows j/j+64/j+128 (48 float4); r,z,n computed
// locally; ONE lgkm-only barrier per step. The compiler remats weight loads
// from L2 per step (unavoidable in HIP source — r8-r15 ablations); this
// structure overlaps them best.
#define DECL_W(i)                                                              \
  float4 W##i; {                                                               \
    float4 t0 = LD4(wg + 4 * (i));                                             \
    float4 t1 = LD4(wg + 64 + 4 * (i));                                        \
    W##i.x = t0.x + t1.x; W##i.y = t0.y + t1.y;                                \
    W##i.z = t0.z + t1.z; W##i.w = t0.w + t1.w;                                \
  }                                                                            \
  PIN4(W##i);
#define DECL_X(i) float4 X##i = LD4(xrow + 4 * (i));
#define PQ(i, q) { DOT4(ac##q, X##i, W##i); X##i = LD4(xnext + 4 * (i)); }
#define DECL_WR(i) float4 WR##i = LD4(wr_ + 4 * (i)); PIN4(WR##i);
#define DECL_WZ(i) float4 WZ##i = LD4(wz_ + 4 * (i)); PIN4(WZ##i);
#define DECL_WN(i) float4 WN##i = LD4(wn_ + 4 * (i)); PIN4(WN##i);
#define CCHUNK(i)                                                              \
  { float4 hc = hs4[(i)];                                                      \
    DOT4(racc, hc, WR##i); DOT4(zacc, hc, WZ##i); DOT4(nacc, hc, WN##i); }

__global__ __launch_bounds__(256, 2) void scan_kernel(
    float* __restrict__ x, const float* __restrict__ delta_gi,
    const int* __restrict__ idxmap,
    const float* __restrict__ w_ih, const float* __restrict__ w_hh,
    const float* __restrict__ b_ih, const float* __restrict__ b_hh)
{
  const int b = blockIdx.x;
  const int tid = threadIdx.x;
  __shared__ __align__(16) float hs[64];
  __shared__ float gib[2][192];
  __shared__ int idxl[512];
  float* xrow = x + (int64_t)b * 32768;

  for (int i = tid; i < 512; i += 256) idxl[i] = idxmap[b * 512 + i];

  if (tid < 192) {
    // ---------------- producer ----------------
    const int g = tid;
    const float* wg = w_ih + g * 128;
    ALL16(DECL_W)
    const float bi = b_ih[g];
    ALL16(DECL_X)          // X = x[0]
    __syncthreads();       // idxl staged, hs inited
    {                      // prologue: gib[0] (and reload X <- x[1])
      float ac0 = bi, ac1 = 0.f, ac2 = 0.f, ac3 = 0.f;
      const float* xnext = xrow + 64;
      ALLQ(PQ)
      float acc = (ac0 + ac1) + (ac2 + ac3);
      const int i0 = idxl[0];
      if (i0 >= 0) acc += delta_gi[(int64_t)i0 * 192 + g];
      gib[0][g] = acc;
    }
    const int idx1 = idxl[1];
    float dgn = 0.f;
    if (idx1 >= 0) dgn = delta_gi[(int64_t)idx1 * 192 + g];
    barrier_lgkm();        // gib[0] published
    for (int t = 0; t < 512; ++t) {
      if (t < 511) {
        const int tn2 = (t + 2 < 512) ? (t + 2) : 511;
        const float* xnext = xrow + tn2 * 64;
        float ac0 = bi + dgn, ac1 = 0.f, ac2 = 0.f, ac3 = 0.f;
        ALLQ(PQ)           // consumes X = x[t+1], reloads X <- x[tn2]
        gib[(t + 1) & 1][g] = (ac0 + ac1) + (ac2 + ac3);
        const int idxn = idxl[tn2];
        dgn = 0.f;
        if (idxn >= 0) dgn = delta_gi[(int64_t)idxn * 192 + g];
      }
      barrier_lgkm();      // gib[t+1] published / h(t) published
    }
  } else {
    // ---------------- consumer ----------------
    const int j = tid - 192;
    const float* wr_ = w_hh + j * 64;
    const float* wz_ = w_hh + (j + 64) * 64;
    const float* wn_ = w_hh + (j + 128) * 64;
    ALL16(DECL_WR)
    ALL16(DECL_WZ)
    ALL16(DECL_WN)
    const float bhr = b_hh[j], bhz = b_hh[j + 64], bhn = b_hh[j + 128];
    float hj = 0.f;
    hs[j] = 0.f;
    __syncthreads();
    __builtin_amdgcn_s_setprio(1);  // consumer wave is the critical path
    barrier_lgkm();
    const float4* hs4 = (const float4*)hs;
    for (int t = 0; t < 512; ++t) {
      const float gr = gib[t & 1][j];
      const float gz = gib[t & 1][64 + j];
      const float gn = gib[t & 1][128 + j];
      float racc = bhr, zacc = bhz, nacc = bhn;
      ALL16(CCHUNK)
      const float r = fsig_(gr + racc);
      const float z = fsig_(gz + zacc);
      const float n = ftanh_(gn + r * nacc);
      hj = (1.f - z) * n + z * hj;
      hs[j] = hj;
      xrow[t * 64 + j] = hj;
      barrier_lgkm();      // h(t) published / next gib published
    }
  }
}

// One block per (path, direction). 7-step GRU, D=68, gates 204.
// graph_emb computed inline from col_sum (graphemb_kernel fused away).
__global__ __launch_bounds__(256) void path_kernel(
    const float* __restrict__ x, const int* __restrict__ paths,
    const float* __restrict__ demands, const float* __restrict__ wd,
    const float* __restrict__ col_sum,
    const float* __restrict__ wih_f, const float* __restrict__ whh_f,
    const float* __restrict__ bih_f, const float* __restrict__ bhh_f,
    const float* __restrict__ wih_b, const float* __restrict__ whh_b,
    const float* __restrict__ bih_b, const float* __restrict__ bhh_b,
    float* __restrict__ h_out)
{
  const int p = blockIdx.x & 63;
  const int dir = blockIdx.x >> 6;
  const int g = threadIdx.x;
  const float* w_ih = dir ? wih_b : wih_f;
  const float* w_hh = dir ? whh_b : whh_f;
  const float* bih = dir ? bih_b : bih_f;
  const float* bhh = dir ? bhh_b : bhh_f;
  __shared__ float feat[7][68], hs[68], rbuf[68], zbuf[68];
  if (g < 64) {  // graph_emb inline: mean over (i,j) = col_sum sum / 512^2
    float s = 0.f;
#pragma unroll 8
    for (int jj = 0; jj < 512; ++jj) s += col_sum[jj * 64 + g];
    hs[g] = s * (1.f / 262144.f);
  } else if (g < 68) {
    hs[g] = 0.f;
  }
  if (g < 68) {
#pragma unroll
    for (int t = 0; t < 7; ++t) {
      const int src = paths[p * 8 + t];
      const int dst = paths[p * 8 + t + 1];
      feat[t][g] = (g < 64) ? x[((int64_t)src * 512 + dst) * 64 + g]
                            : fmaxf(demands[p] * wd[g - 64], 0.f);
    }
  }
  __syncthreads();
  for (int s = 0; s < 7; ++s) {
    const int t = dir ? (6 - s) : s;
    float acc = 0.f, hacc = 0.f;
    if (g < 204) {
      acc = bih[g];
      hacc = bhh[g];
      for (int k = 0; k < 68; ++k) {
        acc += feat[t][k] * w_ih[g * 68 + k];
        hacc += hs[k] * w_hh[g * 68 + k];
      }
    }
    if (g < 68) rbuf[g] = sig_(acc + hacc);
    else if (g < 136) zbuf[g - 68] = sig_(acc + hacc);
    __syncthreads();
    if (g >= 136 && g < 204) {
      const int j = g - 136;
      const float n = tanhf(acc + rbuf[j] * hacc);
      const float z = zbuf[j];
      const float hn = (1.f - z) * n + z * hs[j];
      hs[j] = hn;
    }
    __syncthreads();
  }
  if (g < 68) h_out[(dir * 64 + p) * 68 + g] = hs[g];
}

__global__ __launch_bounds__(64) void combine_kernel(
    const float* __restrict__ h_out, const float* __restrict__ wq,
    const float* __restrict__ bq, float* __restrict__ out)
{
  const int p = threadIdx.x;
  float l = bq[0];
#pragma unroll
  for (int d = 0; d < 68; ++d)
    l += 0.5f * (h_out[p * 68 + d] + h_out[(64 + p) * 68 + d]) * wq[d];
  float mx = l;
#pragma unroll
  for (int off = 32; off > 0; off >>= 1) mx = fmaxf(mx, __shfl_xor(mx, off, 64));
  const float e = expf(l - mx);
  float s = e;
#pragma unroll
  for (int off = 32; off > 0; off >>= 1) s += __shfl_xor(s, off, 64);
  out[p] = e / s;
}

extern "C" void kernel_launch(void* const* d_in, const int* in_sizes, int n_in,
                              void* d_out, int out_size, void* d_ws, size_t ws_size,
                              hipStream_t stream)
{
  const float* adj = (const float*)d_in[0];
  const int* edges = (const int*)d_in[1];
  const int* paths = (const int*)d_in[2];
  const float* demands = (const float*)d_in[3];
  const float* emb_w = (const float*)d_in[4];
  const float* w1s = (const float*)d_in[5];
  const float* w2s = (const float*)d_in[6];
  const float* w3s = (const float*)d_in[7];
  const float* gru_w_ih = (const float*)d_in[8];
  const float* gru_w_hh = (const float*)d_in[9];
  const float* gru_b_ih = (const float*)d_in[10];
  const float* gru_b_hh = (const float*)d_in[11];
  const float* pf_w_ih = (const float*)d_in[12];
  const float* pf_w_hh = (const float*)d_in[13];
  const float* pf_b_ih = (const float*)d_in[14];
  const float* pf_b_hh = (const float*)d_in[15];
  const float* pb_w_ih = (const float*)d_in[16];
  const float* pb_w_hh = (const float*)d_in[17];
  const float* pb_b_ih = (const float*)d_in[18];
  const float* pb_b_hh = (const float*)d_in[19];
  const float* wq = (const float*)d_in[20];
  const float* bq = (const float*)d_in[21];
  const float* wd = (const float*)d_in[22];
  float* out = (float*)d_out;

  // Workspace layout (floats): ~74.6 MB total (known-safe size)
  float* xA = (float*)d_ws;                    // 512*512*64 = 16777216
  float* col_sum = xA + 16777216;              // 32768
  int* col_nz = (int*)(col_sum + 32768);       // 512
  int* idxmap = col_nz + 512;                  // 262144
  float* delta_gi = (float*)(idxmap + 262144); // 8192*192 = 1572864
  float* h_out = delta_gi + 1572864;           // 2*64*68 = 8704

  hipMemsetAsync(idxmap, 0xFF, 262144 * sizeof(int), stream);
  scatter_idx_kernel<<<32, 256, 0, stream>>>(edges, idxmap);
  embed_kernel<<<65536, 256, 0, stream>>>(adj, emb_w, xA);

  for (int t = 0; t < 3; ++t) {
    colsum_kernel<<<512, 256, 0, stream>>>(xA, col_sum, col_nz);
    edge_kernel<<<2048, 256, 0, stream>>>(xA, edges, col_sum, col_nz,
        w1s + t * 4096, w2s + t * 4096, w3s + t * 4096, gru_w_ih, delta_gi);
    scan_kernel<<<512, 256, 0, stream>>>(xA, delta_gi, idxmap,
        gru_w_ih, gru_w_hh, gru_b_ih, gru_b_hh);
  }

  colsum_kernel<<<512, 256, 0, stream>>>(xA, col_sum, col_nz);
  path_kernel<<<128, 256, 0, stream>>>(xA, paths, demands, wd, col_sum,
      pf_w_ih, pf_w_hh, pf_b_ih, pf_b_hh,
      pb_w_ih, pb_w_hh, pb_b_ih, pb_b_hh, h_out);
  combine_kernel<<<1, 64, 0, stream>>>(h_out, wq, bq, out);
}